// Round 3
// baseline (361.473 us; speedup 1.0000x reference)
//
#include <hip/hip_runtime.h>

#define NB 4
#define NS 2048
#define ND 512
#define NH 8
#define NDK 64

typedef __attribute__((ext_vector_type(8))) short bf16x8;
typedef __attribute__((ext_vector_type(4))) short bf16x4;
typedef __attribute__((ext_vector_type(4))) float f32x4;

__device__ inline f32x4 mfma16(bf16x8 a, bf16x8 b, f32x4 c) {
    return __builtin_amdgcn_mfma_f32_16x16x32_bf16(a, b, c, 0, 0, 0);
}
__device__ inline unsigned short f2bf(float f) {
    unsigned u = __float_as_uint(f);
    unsigned r = u + 0x7FFFu + ((u >> 16) & 1u);
    return (unsigned short)(r >> 16);
}
__device__ inline float bf2f(unsigned short h) {
    return __uint_as_float(((unsigned)h) << 16);
}
__device__ inline void splitf(float x, short& hi, short& lo) {
    unsigned short h = f2bf(x);
    hi = (short)h;
    lo = (short)f2bf(x - bf2f(h));
}
__device__ inline float exp2_fast(float x) {
    float r; asm("v_exp_f32 %0, %1" : "=v"(r) : "v"(x)); return r;
}
__device__ inline void gload16(const void* g, void* l) {
    __builtin_amdgcn_global_load_lds(
        (const __attribute__((address_space(1))) unsigned int*)g,
        (__attribute__((address_space(3))) unsigned int*)l, 16, 0, 0);
}

// ---------------------------------------------------------------------------
// prep_split: X f32 -> hi/lo bf16 planes (elementwise, coalesced).
// ---------------------------------------------------------------------------
__global__ __launch_bounds__(256) void prep_split(
    const float* __restrict__ X, short* __restrict__ xh, short* __restrict__ xl)
{
    int i = (blockIdx.x * 256 + threadIdx.x) * 4;
    float4 f = *(const float4*)(X + i);
    short h0,h1,h2,h3,l0,l1,l2,l3;
    splitf(f.x,h0,l0); splitf(f.y,h1,l1); splitf(f.z,h2,l2); splitf(f.w,h3,l3);
    bf16x4 hv = {h0,h1,h2,h3}, lv = {l0,l1,l2,l3};
    *(bf16x4*)(xh + i) = hv;
    *(bf16x4*)(xl + i) = lv;
}

// ---------------------------------------------------------------------------
// proj_kernel: per-head projection GEMM, tile 128m x 64n, 4 waves.
//  z=0: Qh = Xsplit @ WQ[h], 3-term split MFMA -> qhi/qlo linear [B,H,S,DK]
//  z=1: Kh likewise -> kth/ktl in TILE-SWIZZLED layout [(bh,t) 8KB tiles],
//       tile byte = s*128 + ((2*dk) ^ ((s&7)<<4))
//  z=2: Vh = bf16(V) @ WV[h], 1-term -> vtile TRANSPOSED tile-swizzled:
//       tile byte = dk*128 + ((2*s) ^ ((dk&7)<<4))
// Grid 512 (1D) with XCD-chunk swizzle: all 8 heads of an m-tile share an XCD
// so the 8x redundant X reads hit that XCD's L2.
// ---------------------------------------------------------------------------
__global__ __launch_bounds__(256) void proj_kernel(
    const short* __restrict__ xh, const short* __restrict__ xl,
    const float* __restrict__ xf, const float* __restrict__ Wf,
    short* __restrict__ o1, short* __restrict__ o2, int z)
{
    const int orig = blockIdx.x;
    const int wg = (orig & 7) * 64 + (orig >> 3);
    const int mt = wg >> 3, h = wg & 7;
    const int m0 = mt * 128;
    const int tid = threadIdx.x;
    const int w = tid >> 6, lane = tid & 63, c = lane & 15, g = lane >> 4;
    const float* Wp = Wf + (size_t)h * ND * NDK;

    __shared__ __align__(16) short smem[15360];
    short* sxh = smem;            // [128][40]
    short* sxl = smem + 5120;
    short* swh = smem + 10240;    // [64][40]  W^T tile [n][k]
    short* swl = smem + 12800;

    f32x4 acc[2][4];
    #pragma unroll
    for (int i = 0; i < 2; i++)
        #pragma unroll
        for (int j = 0; j < 4; j++) acc[i][j] = f32x4{0.f,0.f,0.f,0.f};

    for (int k0 = 0; k0 < ND; k0 += 32) {
        {   // stage X[128][32] (presplit bf16 copies, or f32->bf16 for V)
            int r = tid >> 1, kq = (tid & 1) * 16;
            if (z < 2) {
                const short* s1 = xh + (size_t)(m0 + r) * ND + k0 + kq;
                const short* s2 = xl + (size_t)(m0 + r) * ND + k0 + kq;
                *(bf16x8*)&sxh[r*40 + kq]     = *(const bf16x8*)s1;
                *(bf16x8*)&sxh[r*40 + kq + 8] = *(const bf16x8*)(s1 + 8);
                *(bf16x8*)&sxl[r*40 + kq]     = *(const bf16x8*)s2;
                *(bf16x8*)&sxl[r*40 + kq + 8] = *(const bf16x8*)(s2 + 8);
            } else {
                const float* s1 = xf + (size_t)(m0 + r) * ND + k0 + kq;
                short tmp[16];
                #pragma unroll
                for (int j = 0; j < 4; j++) {
                    float4 f = ((const float4*)s1)[j];
                    tmp[4*j+0] = (short)f2bf(f.x); tmp[4*j+1] = (short)f2bf(f.y);
                    tmp[4*j+2] = (short)f2bf(f.z); tmp[4*j+3] = (short)f2bf(f.w);
                }
                bf16x8 v0, v1;
                #pragma unroll
                for (int j = 0; j < 8; j++) { v0[j] = tmp[j]; v1[j] = tmp[8+j]; }
                *(bf16x8*)&sxh[r*40 + kq]     = v0;
                *(bf16x8*)&sxh[r*40 + kq + 8] = v1;
            }
        }
        // stage W[32][64] f32 -> transposed split bf16 [64][40]
        #pragma unroll
        for (int i = 0; i < 2; i++) {
            int idx = tid * 2 + i;
            int kr = idx >> 4, c4 = (idx & 15) * 4;
            float4 f = *(const float4*)(Wp + (size_t)(k0 + kr) * NDK + c4);
            if (z < 2) {
                short hh, ll;
                splitf(f.x, hh, ll); swh[(c4+0)*40 + kr] = hh; swl[(c4+0)*40 + kr] = ll;
                splitf(f.y, hh, ll); swh[(c4+1)*40 + kr] = hh; swl[(c4+1)*40 + kr] = ll;
                splitf(f.z, hh, ll); swh[(c4+2)*40 + kr] = hh; swl[(c4+2)*40 + kr] = ll;
                splitf(f.w, hh, ll); swh[(c4+3)*40 + kr] = hh; swl[(c4+3)*40 + kr] = ll;
            } else {
                swh[(c4+0)*40 + kr] = (short)f2bf(f.x);
                swh[(c4+1)*40 + kr] = (short)f2bf(f.y);
                swh[(c4+2)*40 + kr] = (short)f2bf(f.z);
                swh[(c4+3)*40 + kr] = (short)f2bf(f.w);
            }
        }
        __syncthreads();

        bf16x8 ah0 = *(bf16x8*)&sxh[(32*w +      c)*40 + 8*g];
        bf16x8 ah1 = *(bf16x8*)&sxh[(32*w + 16 + c)*40 + 8*g];
        bf16x8 al0, al1;
        if (z < 2) {
            al0 = *(bf16x8*)&sxl[(32*w +      c)*40 + 8*g];
            al1 = *(bf16x8*)&sxl[(32*w + 16 + c)*40 + 8*g];
        }
        #pragma unroll
        for (int nf = 0; nf < 4; nf++) {
            bf16x8 bh = *(bf16x8*)&swh[(c + 16*nf)*40 + 8*g];
            acc[0][nf] = mfma16(ah0, bh, acc[0][nf]);
            acc[1][nf] = mfma16(ah1, bh, acc[1][nf]);
            if (z < 2) {
                bf16x8 bl = *(bf16x8*)&swl[(c + 16*nf)*40 + 8*g];
                acc[0][nf] = mfma16(ah0, bl, acc[0][nf]);
                acc[1][nf] = mfma16(ah1, bl, acc[1][nf]);
                acc[0][nf] = mfma16(al0, bh, acc[0][nf]);
                acc[1][nf] = mfma16(al1, bh, acc[1][nf]);
            }
        }
        __syncthreads();
    }

    if (z == 0) {
        #pragma unroll
        for (int mi = 0; mi < 2; mi++)
            #pragma unroll
            for (int nf = 0; nf < 4; nf++)
                #pragma unroll
                for (int r = 0; r < 4; r++) {
                    int row = m0 + 32*w + 16*mi + 4*g + r;
                    int b_ = row >> 11, s = row & 2047;
                    size_t o = ((size_t)(b_ * NH + h) * NS + s) * NDK + c + 16*nf;
                    short hh, ll; splitf(acc[mi][nf][r], hh, ll);
                    o1[o] = hh; o2[o] = ll;
                }
    } else if (z == 1) {
        const int bh = (m0 >> 11) * NH + h;
        short* ep = smem;   // [128][72]
        #pragma unroll
        for (int pass = 0; pass < 2; pass++) {
            __syncthreads();
            #pragma unroll
            for (int mi = 0; mi < 2; mi++)
                #pragma unroll
                for (int nf = 0; nf < 4; nf++)
                    #pragma unroll
                    for (int r = 0; r < 4; r++) {
                        int rl = 32*w + 16*mi + 4*g + r;
                        short hh, ll; splitf(acc[mi][nf][r], hh, ll);
                        ep[rl*72 + c + 16*nf] = pass ? ll : hh;
                    }
            __syncthreads();
            int rl = tid >> 1, half = tid & 1;
            int s = (m0 & 2047) + rl;
            int t = s >> 6, sr = s & 63;
            char* op = (char*)(pass ? o2 : o1) + ((size_t)bh * 32 + t) * 8192 + sr * 128;
            int sw = (sr & 7) << 4;
            #pragma unroll
            for (int ch = 0; ch < 4; ch++) {
                bf16x8 vv = *(bf16x8*)&ep[rl*72 + half*32 + ch*8];
                *(bf16x8*)(op + ((half*64 + ch*16) ^ sw)) = vv;
            }
        }
    } else {
        const int bh = (m0 >> 11) * NH + h;
        short* ep = smem;   // [128][72] holds [s_local][dk]
        __syncthreads();
        #pragma unroll
        for (int mi = 0; mi < 2; mi++)
            #pragma unroll
            for (int nf = 0; nf < 4; nf++)
                #pragma unroll
                for (int r = 0; r < 4; r++) {
                    int rl = 32*w + 16*mi + 4*g + r;
                    ep[rl*72 + c + 16*nf] = (short)f2bf(acc[mi][nf][r]);
                }
        __syncthreads();
        int dk = tid >> 2, scq = (tid & 3) * 32;
        #pragma unroll
        for (int ch = 0; ch < 4; ch++) {
            int sl = scq + ch*8;
            int s = (m0 & 2047) + sl;
            int t = s >> 6, sr0 = s & 63;
            bf16x8 vv;
            #pragma unroll
            for (int i = 0; i < 8; i++) vv[i] = ep[(sl + i)*72 + dk];
            char* op = (char*)o1 + ((size_t)bh * 32 + t) * 8192 + dk * 128;
            *(bf16x8*)(op + ((2*sr0) ^ ((dk & 7) << 4))) = vv;
        }
    }
}

// ---------------------------------------------------------------------------
// attn_kernel: flash attention per (b,h), 64 q-rows/block (4 waves x 16q).
// K(hi/lo) and V^T staged via global_load_lds from pre-swizzled 8KB tiles;
// all LDS fragment reads use byte ^ ((row&7)<<4) -> bank-balanced b128.
// Online softmax in log2 domain with defer-max (THR=12). P stored truncated
// bf16 into per-wave swizzled pbuf. XCD-chunked grid: 4 bh per XCD.
// ---------------------------------------------------------------------------
__global__ __launch_bounds__(256) void attn_kernel(
    const short* __restrict__ qhi, const short* __restrict__ qlo,
    const short* __restrict__ kth, const short* __restrict__ ktl,
    const short* __restrict__ vtl, short* __restrict__ ao)
{
    const int orig = blockIdx.x;
    const int wg = (orig & 7) * 128 + (orig >> 3);
    const int bh = wg >> 5, qb = (wg & 31) * 64;
    const int tid = threadIdx.x;
    const int w = tid >> 6, lane = tid & 63, c = lane & 15, g = lane >> 4;

    __shared__ __align__(16) short kh_s[64*64];
    __shared__ __align__(16) short kl_s[64*64];
    __shared__ __align__(16) short v_s [64*64];
    __shared__ __align__(16) short pb  [4][16*64];
    char* khb = (char*)kh_s;
    char* klb = (char*)kl_s;
    char* vb  = (char*)v_s;
    char* pwb = (char*)pb[w];

    bf16x8 qh[2], ql[2];
    {
        const size_t qrow = ((size_t)bh * NS + qb + 16*w + c) * NDK;
        qh[0] = *(const bf16x8*)&qhi[qrow + 8*g];
        qh[1] = *(const bf16x8*)&qhi[qrow + 32 + 8*g];
        ql[0] = *(const bf16x8*)&qlo[qrow + 8*g];
        ql[1] = *(const bf16x8*)&qlo[qrow + 32 + 8*g];
    }

    const char* ktb = (const char*)kth + (size_t)bh * 32 * 8192;
    const char* klg = (const char*)ktl + (size_t)bh * 32 * 8192;
    const char* vtb = (const char*)vtl + (size_t)bh * 32 * 8192;

    const float SC = 0.18033688f;   // 0.125 * log2(e)
    float mrow[4], lrow[4];
    f32x4 acc[4];
    #pragma unroll
    for (int r = 0; r < 4; r++) { mrow[r] = -1e30f; lrow[r] = 0.f; }
    #pragma unroll
    for (int nf = 0; nf < 4; nf++) acc[nf] = f32x4{0.f,0.f,0.f,0.f};

    for (int t = 0; t < 32; ++t) {
        size_t toff = (size_t)t * 8192 + w * 2048 + lane * 16;
        gload16(ktb + toff,        (char*)kh_s + w*2048);
        gload16(ktb + toff + 1024, (char*)kh_s + w*2048 + 1024);
        gload16(klg + toff,        (char*)kl_s + w*2048);
        gload16(klg + toff + 1024, (char*)kl_s + w*2048 + 1024);
        gload16(vtb + toff,        (char*)v_s  + w*2048);
        gload16(vtb + toff + 1024, (char*)v_s  + w*2048 + 1024);
        __syncthreads();

        // scores: S[16q x 64s], split 3-term MFMA over dk=64
        f32x4 sc[4];
        #pragma unroll
        for (int sf = 0; sf < 4; sf++) {
            sc[sf] = f32x4{0.f,0.f,0.f,0.f};
            int rowK = c + 16*sf;
            #pragma unroll
            for (int ks = 0; ks < 2; ks++) {
                int cb = (ks*64 + 16*g) ^ ((rowK & 7) << 4);
                bf16x8 kh = *(bf16x8*)(khb + rowK*128 + cb);
                bf16x8 kl = *(bf16x8*)(klb + rowK*128 + cb);
                sc[sf] = mfma16(qh[ks], kh, sc[sf]);
                sc[sf] = mfma16(qh[ks], kl, sc[sf]);
                sc[sf] = mfma16(ql[ks], kh, sc[sf]);
            }
        }

        // online softmax (log2 domain), defer-max
        float tmax[4];
        #pragma unroll
        for (int r = 0; r < 4; r++) {
            sc[0][r] *= SC; sc[1][r] *= SC; sc[2][r] *= SC; sc[3][r] *= SC;
            float v = fmaxf(fmaxf(sc[0][r], sc[1][r]), fmaxf(sc[2][r], sc[3][r]));
            #pragma unroll
            for (int off = 1; off < 16; off <<= 1) v = fmaxf(v, __shfl_xor(v, off));
            tmax[r] = v;
        }
        bool need = (tmax[0] > mrow[0] + 12.f) || (tmax[1] > mrow[1] + 12.f) ||
                    (tmax[2] > mrow[2] + 12.f) || (tmax[3] > mrow[3] + 12.f);
        if (__any(need)) {
            #pragma unroll
            for (int r = 0; r < 4; r++) {
                float mn = fmaxf(mrow[r], tmax[r]);
                float fc = exp2_fast(mrow[r] - mn);
                mrow[r] = mn; lrow[r] *= fc;
                acc[0][r] *= fc; acc[1][r] *= fc; acc[2][r] *= fc; acc[3][r] *= fc;
            }
        }
        float rs[4] = {0.f,0.f,0.f,0.f};
        #pragma unroll
        for (int sf = 0; sf < 4; sf++) {
            #pragma unroll
            for (int r = 0; r < 4; r++) {
                float p = exp2_fast(sc[sf][r] - mrow[r]);
                rs[r] += p;
                int q = 4*g + r;
                *(short*)(pwb + q*128 + ((2*c + 32*sf) ^ ((q & 7) << 4))) =
                    (short)(__float_as_uint(p) >> 16);
            }
        }
        #pragma unroll
        for (int r = 0; r < 4; r++) {
            float t2 = rs[r];
            #pragma unroll
            for (int off = 1; off < 16; off <<= 1) t2 += __shfl_xor(t2, off);
            lrow[r] += t2;
        }

        // PV: out[16q x 64dk] += P[16q x 64s] @ V[64s x 64dk]
        #pragma unroll
        for (int ks = 0; ks < 2; ks++) {
            int cbp = (ks*64 + 16*g) ^ ((c & 7) << 4);
            bf16x8 pa = *(bf16x8*)(pwb + c*128 + cbp);
            #pragma unroll
            for (int nf = 0; nf < 4; nf++) {
                int rowV = c + 16*nf;
                int cbv = (ks*64 + 16*g) ^ ((rowV & 7) << 4);
                bf16x8 vv = *(bf16x8*)(vb + rowV*128 + cbv);
                acc[nf] = mfma16(pa, vv, acc[nf]);
            }
        }
        __syncthreads();
    }

    const int b = bh >> 3, hh = bh & 7;
    #pragma unroll
    for (int r = 0; r < 4; r++) {
        float inv = 1.f / lrow[r];
        int q = qb + 16*w + 4*g + r;
        size_t o = ((size_t)b * NS + q) * ND + hh * NDK;
        #pragma unroll
        for (int nf = 0; nf < 4; nf++)
            ao[o + c + 16*nf] = (short)f2bf(acc[nf][r] * inv);
    }
}

// ---------------------------------------------------------------------------
// oproj_kernel: out[8192x512] = ao(bf16) @ WO(f32->bf16). Tile 128x64.
// XCD-chunked grid so the 8 n-blocks of an m-tile share L2 for ao rows.
// ---------------------------------------------------------------------------
__global__ __launch_bounds__(256) void oproj_kernel(
    const short* __restrict__ ao, const float* __restrict__ WO, float* __restrict__ out)
{
    const int orig = blockIdx.x;
    const int wg = (orig & 7) * 64 + (orig >> 3);
    const int mb = (wg >> 3) * 128, nb = (wg & 7) * 64;
    const int tid = threadIdx.x;
    const int w = tid >> 6, lane = tid & 63, c = lane & 15, g = lane >> 4;

    __shared__ __align__(16) short xlds[128*40];
    __shared__ __align__(16) short wt[64*40];

    f32x4 acc[2][4];
    #pragma unroll
    for (int i = 0; i < 2; i++)
        #pragma unroll
        for (int j = 0; j < 4; j++) acc[i][j] = f32x4{0.f,0.f,0.f,0.f};

    for (int k0 = 0; k0 < ND; k0 += 32) {
        {
            int r = tid >> 1, kq = (tid & 1) * 16;
            const short* src = ao + (size_t)(mb + r) * ND + k0 + kq;
            *(bf16x8*)&xlds[r*40 + kq]     = *(const bf16x8*)src;
            *(bf16x8*)&xlds[r*40 + kq + 8] = *(const bf16x8*)(src + 8);
        }
        #pragma unroll
        for (int i = 0; i < 2; i++) {
            int idx = tid * 2 + i;
            int kr = idx >> 4, c4 = (idx & 15) * 4;
            float4 f = *(const float4*)&WO[(size_t)(k0 + kr) * ND + nb + c4];
            wt[(c4+0)*40 + kr] = (short)f2bf(f.x);
            wt[(c4+1)*40 + kr] = (short)f2bf(f.y);
            wt[(c4+2)*40 + kr] = (short)f2bf(f.z);
            wt[(c4+3)*40 + kr] = (short)f2bf(f.w);
        }
        __syncthreads();
        bf16x8 a0 = *(bf16x8*)&xlds[(32*w +      c)*40 + 8*g];
        bf16x8 a1 = *(bf16x8*)&xlds[(32*w + 16 + c)*40 + 8*g];
        #pragma unroll
        for (int nf = 0; nf < 4; nf++) {
            bf16x8 bv = *(bf16x8*)&wt[(c + 16*nf)*40 + 8*g];
            acc[0][nf] = mfma16(a0, bv, acc[0][nf]);
            acc[1][nf] = mfma16(a1, bv, acc[1][nf]);
        }
        __syncthreads();
    }
    #pragma unroll
    for (int mi = 0; mi < 2; mi++)
        #pragma unroll
        for (int nf = 0; nf < 4; nf++)
            #pragma unroll
            for (int r = 0; r < 4; r++) {
                int row = mb + 32*w + 16*mi + 4*g + r;
                out[(size_t)row * ND + nb + c + 16*nf] = acc[mi][nf][r];
            }
}

extern "C" void kernel_launch(void* const* d_in, const int* in_sizes, int n_in,
                              void* d_out, int out_size, void* d_ws, size_t ws_size,
                              hipStream_t stream) {
    (void)in_sizes; (void)n_in; (void)out_size; (void)ws_size;
    const float* Q  = (const float*)d_in[0];
    const float* K  = (const float*)d_in[1];
    const float* V  = (const float*)d_in[2];
    const float* WQ = (const float*)d_in[3];
    const float* WK = (const float*)d_in[4];
    const float* WV = (const float*)d_in[5];
    const float* WO = (const float*)d_in[6];

    char* ws = (char*)d_ws;
    const size_t PLANE = (size_t)NB * NH * NS * NDK * 2;   // 8,388,608 B
    short* xh    = (short*)(ws);            // region 0: X-hi, later vtile
    short* xl    = (short*)(ws +   PLANE);  // region 1: X-lo, later ao
    short* qhi   = (short*)(ws + 2*PLANE);
    short* qlo   = (short*)(ws + 3*PLANE);
    short* kth   = (short*)(ws + 4*PLANE);
    short* ktl   = (short*)(ws + 5*PLANE);
    short* vtile = xh;   // lifetime-aliased: xh dead after proj(K)
    short* ao    = xl;   // lifetime-aliased: xl dead after proj(K)

    prep_split<<<4096, 256, 0, stream>>>(Q, xh, xl);
    proj_kernel<<<512, 256, 0, stream>>>(xh, xl, nullptr, WQ, qhi, qlo, 0);
    prep_split<<<4096, 256, 0, stream>>>(K, xh, xl);
    proj_kernel<<<512, 256, 0, stream>>>(xh, xl, nullptr, WK, kth, ktl, 1);
    proj_kernel<<<512, 256, 0, stream>>>(nullptr, nullptr, V, WV, vtile, nullptr, 2);
    attn_kernel<<<1024, 256, 0, stream>>>(qhi, qlo, kth, ktl, vtile, ao);
    oproj_kernel<<<512, 256, 0, stream>>>(ao, WO, (float*)d_out);
}

// Round 4
// 295.898 us; speedup vs baseline: 1.2216x; 1.2216x over previous
//
#include <hip/hip_runtime.h>

#define NB 4
#define NS 2048
#define ND 512
#define NH 8
#define NDK 64

typedef __attribute__((ext_vector_type(8))) short bf16x8;
typedef __attribute__((ext_vector_type(4))) short bf16x4;
typedef __attribute__((ext_vector_type(4))) float f32x4;
typedef __attribute__((ext_vector_type(4))) int   i32x4;

__device__ inline f32x4 mfma16(bf16x8 a, bf16x8 b, f32x4 c) {
    return __builtin_amdgcn_mfma_f32_16x16x32_bf16(a, b, c, 0, 0, 0);
}
__device__ inline unsigned short f2bf(float f) {
    unsigned u = __float_as_uint(f);
    unsigned r = u + 0x7FFFu + ((u >> 16) & 1u);
    return (unsigned short)(r >> 16);
}
__device__ inline float bf2f(unsigned short h) {
    return __uint_as_float(((unsigned)h) << 16);
}
__device__ inline void splitf(float x, short& hi, short& lo) {
    unsigned short h = f2bf(x);
    hi = (short)h;
    lo = (short)f2bf(x - bf2f(h));
}
__device__ inline float exp2_fast(float x) {
    float r; asm("v_exp_f32 %0, %1" : "=v"(r) : "v"(x)); return r;
}

// ---------------------------------------------------------------------------
// prep_split: X f32 -> hi/lo bf16 planes (elementwise, coalesced).
// ---------------------------------------------------------------------------
__global__ __launch_bounds__(256) void prep_split(
    const float* __restrict__ X, short* __restrict__ xh, short* __restrict__ xl)
{
    int i = (blockIdx.x * 256 + threadIdx.x) * 4;
    float4 f = *(const float4*)(X + i);
    short h0,h1,h2,h3,l0,l1,l2,l3;
    splitf(f.x,h0,l0); splitf(f.y,h1,l1); splitf(f.z,h2,l2); splitf(f.w,h3,l3);
    bf16x4 hv = {h0,h1,h2,h3}, lv = {l0,l1,l2,l3};
    *(bf16x4*)(xh + i) = hv;
    *(bf16x4*)(xl + i) = lv;
}

// ---------------------------------------------------------------------------
// proj_kernel: per-head projection GEMM, tile 128m x 64n, 4 waves, register
// prefetch of next k-tile (T14). z = zbase + blockIdx.z:
//  z=0: Qh from presplit xq -> qth/qtl tile-swizzled 8KB tiles
//  z=1: Kh from presplit xk -> kth/ktl tile-swizzled
//  z=2: Vh from raw f32 V   -> vt transposed tile-swizzled
// Tile layout (z<2): byte = s*128 + ((2*dk) ^ ((s&7)<<4)) within (bh,t) tile.
// V layout: byte = dk*128 + ((2*s) ^ ((dk&7)<<4)).
// Grid (64,8,*): same m-tile's 8 heads land on one XCD (64%8==0) for L2 reuse.
// ---------------------------------------------------------------------------
__global__ __launch_bounds__(256) void proj_kernel(
    const short* __restrict__ xqh, const short* __restrict__ xql,
    const short* __restrict__ xkh, const short* __restrict__ xkl,
    const float* __restrict__ Vf,
    const float* __restrict__ WQ, const float* __restrict__ WK,
    const float* __restrict__ WV,
    short* __restrict__ qth, short* __restrict__ qtl,
    short* __restrict__ kth, short* __restrict__ ktl,
    short* __restrict__ vt, int zbase)
{
    const int z = zbase + blockIdx.z;
    const int m0 = blockIdx.x * 128;
    const int h  = blockIdx.y;
    const int tid = threadIdx.x;
    const int w = tid >> 6, lane = tid & 63, c = lane & 15, g = lane >> 4;

    const short* xh = (z == 0) ? xqh : xkh;
    const short* xl = (z == 0) ? xql : xkl;
    const float* Wp = ((z == 0) ? WQ : (z == 1) ? WK : WV) + (size_t)h * ND * NDK;
    short* o1 = (z == 0) ? qth : (z == 1) ? kth : vt;
    short* o2 = (z == 0) ? qtl : ktl;

    __shared__ __align__(16) short smem[15360];
    short* sxh = smem;            // [128][40]
    short* sxl = smem + 5120;
    short* swh = smem + 10240;    // [64][40]  W^T tile [n][k]
    short* swl = smem + 12800;

    f32x4 acc[2][4];
    #pragma unroll
    for (int i = 0; i < 2; i++)
        #pragma unroll
        for (int j = 0; j < 4; j++) acc[i][j] = f32x4{0.f,0.f,0.f,0.f};

    const int r_ = tid >> 1, kq = (tid & 1) * 16;
    const int kr0 = (tid*2) >> 4,     c40 = ((tid*2) & 15) * 4;
    const int kr1 = (tid*2+1) >> 4,   c41 = ((tid*2+1) & 15) * 4;

    bf16x8 rh0, rh1, rl0, rl1;
    float4 rv0, rv1, rv2, rv3;
    float4 rw0, rw1;

    auto LDX = [&](int k0) {
        if (z < 2) {
            const short* s1 = xh + (size_t)(m0 + r_) * ND + k0 + kq;
            const short* s2 = xl + (size_t)(m0 + r_) * ND + k0 + kq;
            rh0 = *(const bf16x8*)s1; rh1 = *(const bf16x8*)(s1 + 8);
            rl0 = *(const bf16x8*)s2; rl1 = *(const bf16x8*)(s2 + 8);
        } else {
            const float* s1 = Vf + (size_t)(m0 + r_) * ND + k0 + kq;
            rv0 = ((const float4*)s1)[0]; rv1 = ((const float4*)s1)[1];
            rv2 = ((const float4*)s1)[2]; rv3 = ((const float4*)s1)[3];
        }
    };
    auto LDW = [&](int k0) {
        rw0 = *(const float4*)(Wp + (size_t)(k0 + kr0) * NDK + c40);
        rw1 = *(const float4*)(Wp + (size_t)(k0 + kr1) * NDK + c41);
    };

    LDX(0); LDW(0);

    for (int k0 = 0; k0 < ND; k0 += 32) {
        // ---- write staged regs -> LDS ----
        if (z < 2) {
            *(bf16x8*)&sxh[r_*40 + kq]     = rh0;
            *(bf16x8*)&sxh[r_*40 + kq + 8] = rh1;
            *(bf16x8*)&sxl[r_*40 + kq]     = rl0;
            *(bf16x8*)&sxl[r_*40 + kq + 8] = rl1;
            short hh, ll;
            splitf(rw0.x, hh, ll); swh[(c40+0)*40 + kr0] = hh; swl[(c40+0)*40 + kr0] = ll;
            splitf(rw0.y, hh, ll); swh[(c40+1)*40 + kr0] = hh; swl[(c40+1)*40 + kr0] = ll;
            splitf(rw0.z, hh, ll); swh[(c40+2)*40 + kr0] = hh; swl[(c40+2)*40 + kr0] = ll;
            splitf(rw0.w, hh, ll); swh[(c40+3)*40 + kr0] = hh; swl[(c40+3)*40 + kr0] = ll;
            splitf(rw1.x, hh, ll); swh[(c41+0)*40 + kr1] = hh; swl[(c41+0)*40 + kr1] = ll;
            splitf(rw1.y, hh, ll); swh[(c41+1)*40 + kr1] = hh; swl[(c41+1)*40 + kr1] = ll;
            splitf(rw1.z, hh, ll); swh[(c41+2)*40 + kr1] = hh; swl[(c41+2)*40 + kr1] = ll;
            splitf(rw1.w, hh, ll); swh[(c41+3)*40 + kr1] = hh; swl[(c41+3)*40 + kr1] = ll;
        } else {
            short tmp[16];
            tmp[0]=(short)f2bf(rv0.x); tmp[1]=(short)f2bf(rv0.y);
            tmp[2]=(short)f2bf(rv0.z); tmp[3]=(short)f2bf(rv0.w);
            tmp[4]=(short)f2bf(rv1.x); tmp[5]=(short)f2bf(rv1.y);
            tmp[6]=(short)f2bf(rv1.z); tmp[7]=(short)f2bf(rv1.w);
            tmp[8]=(short)f2bf(rv2.x); tmp[9]=(short)f2bf(rv2.y);
            tmp[10]=(short)f2bf(rv2.z); tmp[11]=(short)f2bf(rv2.w);
            tmp[12]=(short)f2bf(rv3.x); tmp[13]=(short)f2bf(rv3.y);
            tmp[14]=(short)f2bf(rv3.z); tmp[15]=(short)f2bf(rv3.w);
            bf16x8 v0, v1;
            #pragma unroll
            for (int j = 0; j < 8; j++) { v0[j] = tmp[j]; v1[j] = tmp[8+j]; }
            *(bf16x8*)&sxh[r_*40 + kq]     = v0;
            *(bf16x8*)&sxh[r_*40 + kq + 8] = v1;
            swh[(c40+0)*40 + kr0] = (short)f2bf(rw0.x);
            swh[(c40+1)*40 + kr0] = (short)f2bf(rw0.y);
            swh[(c40+2)*40 + kr0] = (short)f2bf(rw0.z);
            swh[(c40+3)*40 + kr0] = (short)f2bf(rw0.w);
            swh[(c41+0)*40 + kr1] = (short)f2bf(rw1.x);
            swh[(c41+1)*40 + kr1] = (short)f2bf(rw1.y);
            swh[(c41+2)*40 + kr1] = (short)f2bf(rw1.z);
            swh[(c41+3)*40 + kr1] = (short)f2bf(rw1.w);
        }
        __syncthreads();

        if (k0 + 32 < ND) { LDX(k0 + 32); LDW(k0 + 32); }

        bf16x8 ah0 = *(bf16x8*)&sxh[(32*w +      c)*40 + 8*g];
        bf16x8 ah1 = *(bf16x8*)&sxh[(32*w + 16 + c)*40 + 8*g];
        bf16x8 al0, al1;
        if (z < 2) {
            al0 = *(bf16x8*)&sxl[(32*w +      c)*40 + 8*g];
            al1 = *(bf16x8*)&sxl[(32*w + 16 + c)*40 + 8*g];
        }
        #pragma unroll
        for (int nf = 0; nf < 4; nf++) {
            bf16x8 bh = *(bf16x8*)&swh[(c + 16*nf)*40 + 8*g];
            acc[0][nf] = mfma16(ah0, bh, acc[0][nf]);
            acc[1][nf] = mfma16(ah1, bh, acc[1][nf]);
            if (z < 2) {
                bf16x8 bl = *(bf16x8*)&swl[(c + 16*nf)*40 + 8*g];
                acc[0][nf] = mfma16(ah0, bl, acc[0][nf]);
                acc[1][nf] = mfma16(ah1, bl, acc[1][nf]);
                acc[0][nf] = mfma16(al0, bh, acc[0][nf]);
                acc[1][nf] = mfma16(al1, bh, acc[1][nf]);
            }
        }
        __syncthreads();
    }

    const int bh = (m0 >> 11) * NH + h;
    if (z < 2) {
        short* ep = smem;   // [128][72]
        #pragma unroll
        for (int pass = 0; pass < 2; pass++) {
            __syncthreads();
            #pragma unroll
            for (int mi = 0; mi < 2; mi++)
                #pragma unroll
                for (int nf = 0; nf < 4; nf++)
                    #pragma unroll
                    for (int r = 0; r < 4; r++) {
                        int rl = 32*w + 16*mi + 4*g + r;
                        short hh, ll; splitf(acc[mi][nf][r], hh, ll);
                        ep[rl*72 + c + 16*nf] = pass ? ll : hh;
                    }
            __syncthreads();
            int rl = tid >> 1, half = tid & 1;
            int s = (m0 & 2047) + rl;
            int t = s >> 6, sr = s & 63;
            char* op = (char*)(pass ? o2 : o1) + ((size_t)bh * 32 + t) * 8192 + sr * 128;
            int sw = (sr & 7) << 4;
            #pragma unroll
            for (int ch = 0; ch < 4; ch++) {
                bf16x8 vv = *(bf16x8*)&ep[rl*72 + half*32 + ch*8];
                *(bf16x8*)(op + ((half*64 + ch*16) ^ sw)) = vv;
            }
        }
    } else {
        short* ep = smem;   // [128][72] holds [s_local][dk]
        __syncthreads();
        #pragma unroll
        for (int mi = 0; mi < 2; mi++)
            #pragma unroll
            for (int nf = 0; nf < 4; nf++)
                #pragma unroll
                for (int r = 0; r < 4; r++) {
                    int rl = 32*w + 16*mi + 4*g + r;
                    ep[rl*72 + c + 16*nf] = (short)f2bf(acc[mi][nf][r]);
                }
        __syncthreads();
        int dk = tid >> 2, scq = (tid & 3) * 32;
        #pragma unroll
        for (int ch = 0; ch < 4; ch++) {
            int sl = scq + ch*8;
            int s = (m0 & 2047) + sl;
            int t = s >> 6, sr0 = s & 63;
            bf16x8 vv;
            #pragma unroll
            for (int i = 0; i < 8; i++) vv[i] = ep[(sl + i)*72 + dk];
            char* op = (char*)o1 + ((size_t)bh * 32 + t) * 8192 + dk * 128;
            *(bf16x8*)(op + ((2*sr0) ^ ((dk & 7) << 4))) = vv;
        }
    }
}

// ---------------------------------------------------------------------------
// attn_kernel v4: flash attention, 64 q-rows/block (4 waves x 16q).
// Register-staged K/V pipeline (T3-min/T14): tile t+1's 6 global 16B loads
// issued right after tile t's LDS is published; ds_write+barrier at tile top.
// Raw-score-domain online softmax, deferred lrow reduction, wave-uniform
// tile-skip when whole tile is < 2^-26 of running max. Swizzled zero-conflict
// LDS. Q read directly from swizzled tiles.
// ---------------------------------------------------------------------------
__global__ __launch_bounds__(256, 4) void attn_kernel(
    const short* __restrict__ qth, const short* __restrict__ qtl,
    const short* __restrict__ kth, const short* __restrict__ ktl,
    const short* __restrict__ vtl, short* __restrict__ ao)
{
    const int orig = blockIdx.x;
    const int wg = (orig & 7) * 128 + (orig >> 3);
    const int bh = wg >> 5, qb = (wg & 31) * 64;
    const int tid = threadIdx.x;
    const int w = tid >> 6, lane = tid & 63, c = lane & 15, g = lane >> 4;

    __shared__ __align__(16) short kh_s[64*64];
    __shared__ __align__(16) short kl_s[64*64];
    __shared__ __align__(16) short v_s [64*64];
    __shared__ __align__(16) short pb  [4][16*64];
    char* khb = (char*)kh_s;
    char* klb = (char*)kl_s;
    char* vb  = (char*)v_s;
    char* pwb = (char*)pb[w];
    short* pw = pb[w];

    // Q fragments from swizzled tiles (hi/lo, 2 k-steps)
    bf16x8 qh[2], ql[2];
    {
        const char* qtbh = (const char*)qth + ((size_t)bh*32 + (qb>>6))*8192;
        const char* qtbl = (const char*)qtl + ((size_t)bh*32 + (qb>>6))*8192;
        int s_in = 16*w + c;
        int sw = (s_in & 7) << 4;
        qh[0] = *(const bf16x8*)(qtbh + s_in*128 + ((16*g) ^ sw));
        qh[1] = *(const bf16x8*)(qtbh + s_in*128 + ((64 + 16*g) ^ sw));
        ql[0] = *(const bf16x8*)(qtbl + s_in*128 + ((16*g) ^ sw));
        ql[1] = *(const bf16x8*)(qtbl + s_in*128 + ((64 + 16*g) ^ sw));
    }

    const char* kg = (const char*)kth + (size_t)bh * 262144;
    const char* lg = (const char*)ktl + (size_t)bh * 262144;
    const char* vg = (const char*)vtl + (size_t)bh * 262144;
    const int thr = w * 2048 + lane * 16;

    const float SC = 0.18033688f;   // 0.125 * log2(e)
    float mrow[4], lrowp[4];
    f32x4 acc[4];
    #pragma unroll
    for (int r = 0; r < 4; r++) { mrow[r] = -1e30f; lrowp[r] = 0.f; }
    #pragma unroll
    for (int nf = 0; nf < 4; nf++) acc[nf] = f32x4{0.f,0.f,0.f,0.f};

    i32x4 s0, s1, s2, s3, s4, s5;
    {
        const char* p = kg + thr; s0 = *(const i32x4*)p; s1 = *(const i32x4*)(p + 1024);
        p = lg + thr;             s2 = *(const i32x4*)p; s3 = *(const i32x4*)(p + 1024);
        p = vg + thr;             s4 = *(const i32x4*)p; s5 = *(const i32x4*)(p + 1024);
    }

    for (int t = 0; t < 32; ++t) {
        {   // publish staged regs -> LDS
            char* d = khb + thr; *(i32x4*)d = s0; *(i32x4*)(d + 1024) = s1;
            d = klb + thr;       *(i32x4*)d = s2; *(i32x4*)(d + 1024) = s3;
            d = vb + thr;        *(i32x4*)d = s4; *(i32x4*)(d + 1024) = s5;
        }
        __syncthreads();
        if (t < 31) {   // prefetch next tile into regs (hides under compute)
            size_t off = (size_t)(t + 1) * 8192 + thr;
            const char* p = kg + off; s0 = *(const i32x4*)p; s1 = *(const i32x4*)(p + 1024);
            p = lg + off;             s2 = *(const i32x4*)p; s3 = *(const i32x4*)(p + 1024);
            p = vg + off;             s4 = *(const i32x4*)p; s5 = *(const i32x4*)(p + 1024);
        }

        // scores: S[16q x 64s], split 3-term MFMA over dk=64 (raw domain)
        f32x4 s4c[4];
        #pragma unroll
        for (int sf = 0; sf < 4; sf++) {
            s4c[sf] = f32x4{0.f,0.f,0.f,0.f};
            int rowK = c + 16*sf;
            #pragma unroll
            for (int ks = 0; ks < 2; ks++) {
                int cb = (ks*64 + 16*g) ^ ((rowK & 7) << 4);
                bf16x8 kh = *(bf16x8*)(khb + rowK*128 + cb);
                bf16x8 kl = *(bf16x8*)(klb + rowK*128 + cb);
                s4c[sf] = mfma16(qh[ks], kh, s4c[sf]);
                s4c[sf] = mfma16(qh[ks], kl, s4c[sf]);
                s4c[sf] = mfma16(ql[ks], kh, s4c[sf]);
            }
        }

        // per-row tile max (raw domain)
        float tmax[4];
        #pragma unroll
        for (int r = 0; r < 4; r++) {
            float v = fmaxf(fmaxf(s4c[0][r], s4c[1][r]), fmaxf(s4c[2][r], s4c[3][r]));
            #pragma unroll
            for (int off = 1; off < 16; off <<= 1) v = fmaxf(v, __shfl_xor(v, off));
            tmax[r] = v;
        }
        float dmax = fmaxf(fmaxf(tmax[0]-mrow[0], tmax[1]-mrow[1]),
                           fmaxf(tmax[2]-mrow[2], tmax[3]-mrow[3]));
        // skip tile if contribution < 2^-26 of running max for every row
        if (!__all(dmax < -144.0f)) {
            if (__any(dmax > 64.0f)) {   // defer-max rescale (~11.5 log2 units)
                #pragma unroll
                for (int r = 0; r < 4; r++) {
                    float mn = fmaxf(mrow[r], tmax[r]);
                    float fc = exp2_fast((mrow[r] - mn) * SC);
                    mrow[r] = mn; lrowp[r] *= fc;
                    acc[0][r] *= fc; acc[1][r] *= fc; acc[2][r] *= fc; acc[3][r] *= fc;
                }
            }
            float mS[4];
            #pragma unroll
            for (int r = 0; r < 4; r++) mS[r] = mrow[r] * SC;
            float rs[4] = {0.f, 0.f, 0.f, 0.f};
            #pragma unroll
            for (int sf = 0; sf < 4; sf++) {
                #pragma unroll
                for (int r = 0; r < 4; r++) {
                    float p = exp2_fast(fmaf(s4c[sf][r], SC, -mS[r]));
                    rs[r] += p;
                    int q = 4*g + r;
                    *(short*)(pwb + q*128 + ((2*c + 32*sf) ^ ((q & 7) << 4))) =
                        (short)(__float_as_uint(p) >> 16);
                }
            }
            #pragma unroll
            for (int r = 0; r < 4; r++) lrowp[r] += rs[r];   // per-lane partial

            // PV: out[16q x 64dk] += P[16q x 64s] @ V[64s x 64dk]
            #pragma unroll
            for (int ks = 0; ks < 2; ks++) {
                int cbp = (ks*64 + 16*g) ^ ((c & 7) << 4);
                bf16x8 pa = *(bf16x8*)(pwb + c*128 + cbp);
                #pragma unroll
                for (int nf = 0; nf < 4; nf++) {
                    int rowV = c + 16*nf;
                    int cbv = (ks*64 + 16*g) ^ ((rowV & 7) << 4);
                    bf16x8 vv = *(bf16x8*)(vb + rowV*128 + cbv);
                    acc[nf] = mfma16(pa, vv, acc[nf]);
                }
            }
        }
        __syncthreads();
    }

    // epilogue: cross-lane lrow reduction, normalize, LDS-transpose, 16B stores
    float inv[4];
    #pragma unroll
    for (int r = 0; r < 4; r++) {
        float t2 = lrowp[r];
        #pragma unroll
        for (int off = 1; off < 16; off <<= 1) t2 += __shfl_xor(t2, off);
        inv[r] = 1.f / t2;
    }
    #pragma unroll
    for (int nf = 0; nf < 4; nf++)
        #pragma unroll
        for (int r = 0; r < 4; r++)
            pw[(4*g + r)*64 + c + 16*nf] = (short)f2bf(acc[nf][r] * inv[r]);

    const int b = bh >> 3, hh = bh & 7;
    {
        int q = qb + 16*w + c;
        size_t o = ((size_t)b * NS + q) * ND + hh * NDK + g * 16;
        const short* src = pw + c*64 + g*16;
        *(bf16x8*)&ao[o]     = *(const bf16x8*)src;
        *(bf16x8*)&ao[o + 8] = *(const bf16x8*)(src + 8);
    }
}

// ---------------------------------------------------------------------------
// oproj_kernel: out[8192x512] = ao(bf16) @ WO(f32->bf16). Tile 128x64.
// ---------------------------------------------------------------------------
__global__ __launch_bounds__(256) void oproj_kernel(
    const short* __restrict__ ao, const float* __restrict__ WO, float* __restrict__ out)
{
    const int orig = blockIdx.x;
    const int wg = (orig & 7) * 64 + (orig >> 3);
    const int mb = (wg >> 3) * 128, nb = (wg & 7) * 64;
    const int tid = threadIdx.x;
    const int w = tid >> 6, lane = tid & 63, c = lane & 15, g = lane >> 4;

    __shared__ __align__(16) short xlds[128*40];
    __shared__ __align__(16) short wt[64*40];

    f32x4 acc[2][4];
    #pragma unroll
    for (int i = 0; i < 2; i++)
        #pragma unroll
        for (int j = 0; j < 4; j++) acc[i][j] = f32x4{0.f,0.f,0.f,0.f};

    for (int k0 = 0; k0 < ND; k0 += 32) {
        {
            int r = tid >> 1, kq = (tid & 1) * 16;
            const short* src = ao + (size_t)(mb + r) * ND + k0 + kq;
            *(bf16x8*)&xlds[r*40 + kq]     = *(const bf16x8*)src;
            *(bf16x8*)&xlds[r*40 + kq + 8] = *(const bf16x8*)(src + 8);
        }
        #pragma unroll
        for (int i = 0; i < 2; i++) {
            int idx = tid * 2 + i;
            int kr = idx >> 4, c4 = (idx & 15) * 4;
            float4 f = *(const float4*)&WO[(size_t)(k0 + kr) * ND + nb + c4];
            wt[(c4+0)*40 + kr] = (short)f2bf(f.x);
            wt[(c4+1)*40 + kr] = (short)f2bf(f.y);
            wt[(c4+2)*40 + kr] = (short)f2bf(f.z);
            wt[(c4+3)*40 + kr] = (short)f2bf(f.w);
        }
        __syncthreads();
        bf16x8 a0 = *(bf16x8*)&xlds[(32*w +      c)*40 + 8*g];
        bf16x8 a1 = *(bf16x8*)&xlds[(32*w + 16 + c)*40 + 8*g];
        #pragma unroll
        for (int nf = 0; nf < 4; nf++) {
            bf16x8 bv = *(bf16x8*)&wt[(c + 16*nf)*40 + 8*g];
            acc[0][nf] = mfma16(a0, bv, acc[0][nf]);
            acc[1][nf] = mfma16(a1, bv, acc[1][nf]);
        }
        __syncthreads();
    }
    #pragma unroll
    for (int mi = 0; mi < 2; mi++)
        #pragma unroll
        for (int nf = 0; nf < 4; nf++)
            #pragma unroll
            for (int r = 0; r < 4; r++) {
                int row = mb + 32*w + 16*mi + 4*g + r;
                out[(size_t)row * ND + nb + c + 16*nf] = acc[mi][nf][r];
            }
}

extern "C" void kernel_launch(void* const* d_in, const int* in_sizes, int n_in,
                              void* d_out, int out_size, void* d_ws, size_t ws_size,
                              hipStream_t stream) {
    (void)in_sizes; (void)n_in; (void)out_size;
    const float* Q  = (const float*)d_in[0];
    const float* K  = (const float*)d_in[1];
    const float* V  = (const float*)d_in[2];
    const float* WQ = (const float*)d_in[3];
    const float* WK = (const float*)d_in[4];
    const float* WV = (const float*)d_in[5];
    const float* WO = (const float*)d_in[6];

    char* ws = (char*)d_ws;
    const size_t PLANE = (size_t)NB * NH * NS * NDK * 2;   // 8,388,608 B
    #define P(i) ((short*)(ws + (size_t)(i) * PLANE))

    if (ws_size >= 9 * PLANE) {
        // schedule A: 5 launches, merged projection
        short *xqh=P(0), *xql=P(1), *xkh=P(2), *xkl=P(3);
        short *qth=P(4), *qtl=P(5), *kth=P(6), *ktl=P(7), *vt=P(8);
        short *ao = P(0);   // xq planes dead after proj
        prep_split<<<4096, 256, 0, stream>>>(Q, xqh, xql);
        prep_split<<<4096, 256, 0, stream>>>(K, xkh, xkl);
        proj_kernel<<<dim3(64, NH, 3), 256, 0, stream>>>(
            xqh, xql, xkh, xkl, V, WQ, WK, WV, qth, qtl, kth, ktl, vt, 0);
        attn_kernel<<<1024, 256, 0, stream>>>(qth, qtl, kth, ktl, vt, ao);
        oproj_kernel<<<512, 256, 0, stream>>>(ao, WO, (float*)d_out);
    } else {
        // schedule B: 6-plane budget (proven at 50.3 MB), sequential projs
        short *xh=P(0), *xl=P(1);
        short *qth=P(2), *qtl=P(3), *kth=P(4), *ktl=P(5);
        short *vt=P(0), *ao=P(1);
        prep_split<<<4096, 256, 0, stream>>>(Q, xh, xl);
        proj_kernel<<<dim3(64, NH, 1), 256, 0, stream>>>(
            xh, xl, xh, xl, V, WQ, WK, WV, qth, qtl, kth, ktl, vt, 0);
        prep_split<<<4096, 256, 0, stream>>>(K, xh, xl);
        proj_kernel<<<dim3(64, NH, 1), 256, 0, stream>>>(
            xh, xl, xh, xl, V, WQ, WK, WV, qth, qtl, kth, ktl, vt, 1);
        proj_kernel<<<dim3(64, NH, 1), 256, 0, stream>>>(
            xh, xl, xh, xl, V, WQ, WK, WV, qth, qtl, kth, ktl, vt, 2);
        attn_kernel<<<1024, 256, 0, stream>>>(qth, qtl, kth, ktl, vt, ao);
        oproj_kernel<<<512, 256, 0, stream>>>(ao, WO, (float*)d_out);
    }
    #undef P
}

// Round 5
// 274.428 us; speedup vs baseline: 1.3172x; 1.0782x over previous
//
#include <hip/hip_runtime.h>

#define NB 4
#define NS 2048
#define ND 512
#define NH 8
#define NDK 64

typedef __attribute__((ext_vector_type(8))) short bf16x8;
typedef __attribute__((ext_vector_type(4))) short bf16x4;
typedef __attribute__((ext_vector_type(4))) float f32x4;
typedef __attribute__((ext_vector_type(4))) int   i32x4;

__device__ inline f32x4 mfma16(bf16x8 a, bf16x8 b, f32x4 c) {
    return __builtin_amdgcn_mfma_f32_16x16x32_bf16(a, b, c, 0, 0, 0);
}
__device__ inline unsigned short f2bf(float f) {
    unsigned u = __float_as_uint(f);
    unsigned r = u + 0x7FFFu + ((u >> 16) & 1u);
    return (unsigned short)(r >> 16);
}
__device__ inline float bf2f(unsigned short h) {
    return __uint_as_float(((unsigned)h) << 16);
}
__device__ inline void splitf(float x, short& hi, short& lo) {
    unsigned short h = f2bf(x);
    hi = (short)h;
    lo = (short)f2bf(x - bf2f(h));
}
__device__ inline float exp2_fast(float x) {
    float r; asm("v_exp_f32 %0, %1" : "=v"(r) : "v"(x)); return r;
}

// ---------------------------------------------------------------------------
// prep_w: weights -> B-layout planes [n=h*64+dk][k=d], split bf16 hi/lo for
// WQ/WK, single bf16 for WV. Outputs live in d_out scratch (dead until oproj).
// ---------------------------------------------------------------------------
__global__ __launch_bounds__(256) void prep_w(
    const float* __restrict__ WQ, const float* __restrict__ WK,
    const float* __restrict__ WV,
    short* __restrict__ wqh, short* __restrict__ wql,
    short* __restrict__ wkh, short* __restrict__ wkl, short* __restrict__ wv)
{
    const int z = blockIdx.y;
    const int gid = blockIdx.x * 256 + threadIdx.x;      // 0..65535
    const int idx = gid * 4;                             // element index
    const int dk = idx & 63;
    const int d  = (idx >> 6) & 511;
    const int h  = idx >> 15;
    const float* src = ((z == 0) ? WQ : (z == 1) ? WK : WV) + idx;
    float4 f = *(const float4*)src;
    size_t o = (size_t)(h * 64 + dk) * 512 + d;          // row n, col d
    if (z < 2) {
        short* oh = z ? wkh : wqh;
        short* ol = z ? wkl : wql;
        short hh, ll;
        splitf(f.x, hh, ll); oh[o]        = hh; ol[o]        = ll;
        splitf(f.y, hh, ll); oh[o +  512] = hh; ol[o +  512] = ll;
        splitf(f.z, hh, ll); oh[o + 1024] = hh; ol[o + 1024] = ll;
        splitf(f.w, hh, ll); oh[o + 1536] = hh; ol[o + 1536] = ll;
    } else {
        wv[o]        = (short)f2bf(f.x);
        wv[o +  512] = (short)f2bf(f.y);
        wv[o + 1024] = (short)f2bf(f.z);
        wv[o + 1536] = (short)f2bf(f.w);
    }
}

// ---------------------------------------------------------------------------
// proj: merged projection GEMM, tile 128m x 128n (2 heads per n-tile), K=512.
// z=0: Qh (3-term split) -> qth/qtl swizzled 8KB tiles
// z=1: Kh (3-term split) -> kth/ktl
// z=2: Vh (1-term)       -> vt transposed swizzled tiles
// 4 waves (2x2), each 64x64 (acc 4x4). Register prefetch: next k-tile's X
// (f32, split in-reg) + W (pre-split copies) loaded during current compute.
// ---------------------------------------------------------------------------
__global__ __launch_bounds__(256, 2) void proj(
    const float* __restrict__ Q, const float* __restrict__ K,
    const float* __restrict__ V,
    const short* __restrict__ wqh, const short* __restrict__ wql,
    const short* __restrict__ wkh, const short* __restrict__ wkl,
    const short* __restrict__ wvp,
    short* __restrict__ qth, short* __restrict__ qtl,
    short* __restrict__ kth, short* __restrict__ ktl, short* __restrict__ vt)
{
    const int z  = blockIdx.z;
    const int m0 = blockIdx.x * 128;
    const int nb = blockIdx.y * 128;
    const int tid = threadIdx.x;
    const int w = tid >> 6, lane = tid & 63, c = lane & 15, g = lane >> 4;
    const int wm = w >> 1, wn = w & 1;

    const float* X  = (z == 0) ? Q : (z == 1) ? K : V;
    const short* Wh = (z == 0) ? wqh : (z == 1) ? wkh : wvp;
    const short* Wl = (z == 0) ? wql : wkl;

    __shared__ __align__(16) short smem[20480];   // 40 KB
    short* sxh = smem;            // [128][40]
    short* sxl = smem + 5120;
    short* swh = smem + 10240;
    short* swl = smem + 15360;

    f32x4 acc[4][4];
    #pragma unroll
    for (int i = 0; i < 4; i++)
        #pragma unroll
        for (int j = 0; j < 4; j++) acc[i][j] = f32x4{0.f, 0.f, 0.f, 0.f};

    const int r_ = tid >> 1, kq = (tid & 1) * 16;

    bf16x8 axh0, axh1, axl0, axl1;
    bf16x8 awh0, awh1, awl0, awl1;

    auto LD = [&](int k0) {
        const float* s1 = X + (size_t)(m0 + r_) * ND + k0 + kq;
        float4 f0 = ((const float4*)s1)[0];
        float4 f1 = ((const float4*)s1)[1];
        float4 f2 = ((const float4*)s1)[2];
        float4 f3 = ((const float4*)s1)[3];
        float xv[16] = {f0.x,f0.y,f0.z,f0.w, f1.x,f1.y,f1.z,f1.w,
                        f2.x,f2.y,f2.z,f2.w, f3.x,f3.y,f3.z,f3.w};
        short hv[16], lv[16];
        if (z < 2) {
            #pragma unroll
            for (int j = 0; j < 16; j++) splitf(xv[j], hv[j], lv[j]);
        } else {
            #pragma unroll
            for (int j = 0; j < 16; j++) hv[j] = (short)f2bf(xv[j]);
        }
        #pragma unroll
        for (int j = 0; j < 8; j++) {
            axh0[j] = hv[j]; axh1[j] = hv[8 + j];
            if (z < 2) { axl0[j] = lv[j]; axl1[j] = lv[8 + j]; }
        }
        const short* ws1 = Wh + (size_t)(nb + r_) * ND + k0 + kq;
        awh0 = *(const bf16x8*)ws1; awh1 = *(const bf16x8*)(ws1 + 8);
        if (z < 2) {
            const short* ws2 = Wl + (size_t)(nb + r_) * ND + k0 + kq;
            awl0 = *(const bf16x8*)ws2; awl1 = *(const bf16x8*)(ws2 + 8);
        }
    };

    LD(0);

    for (int k0 = 0; k0 < ND; k0 += 32) {
        *(bf16x8*)&sxh[r_*40 + kq]     = axh0;
        *(bf16x8*)&sxh[r_*40 + kq + 8] = axh1;
        *(bf16x8*)&swh[r_*40 + kq]     = awh0;
        *(bf16x8*)&swh[r_*40 + kq + 8] = awh1;
        if (z < 2) {
            *(bf16x8*)&sxl[r_*40 + kq]     = axl0;
            *(bf16x8*)&sxl[r_*40 + kq + 8] = axl1;
            *(bf16x8*)&swl[r_*40 + kq]     = awl0;
            *(bf16x8*)&swl[r_*40 + kq + 8] = awl1;
        }
        __syncthreads();
        if (k0 + 32 < ND) LD(k0 + 32);

        bf16x8 ah[4], al[4];
        #pragma unroll
        for (int mi = 0; mi < 4; mi++) {
            ah[mi] = *(bf16x8*)&sxh[(64*wm + 16*mi + c)*40 + 8*g];
            if (z < 2) al[mi] = *(bf16x8*)&sxl[(64*wm + 16*mi + c)*40 + 8*g];
        }
        #pragma unroll
        for (int nf = 0; nf < 4; nf++) {
            bf16x8 bh = *(bf16x8*)&swh[(64*wn + 16*nf + c)*40 + 8*g];
            if (z < 2) {
                bf16x8 bl = *(bf16x8*)&swl[(64*wn + 16*nf + c)*40 + 8*g];
                #pragma unroll
                for (int mi = 0; mi < 4; mi++) {
                    acc[mi][nf] = mfma16(ah[mi], bh, acc[mi][nf]);
                    acc[mi][nf] = mfma16(ah[mi], bl, acc[mi][nf]);
                    acc[mi][nf] = mfma16(al[mi], bh, acc[mi][nf]);
                }
            } else {
                #pragma unroll
                for (int mi = 0; mi < 4; mi++)
                    acc[mi][nf] = mfma16(ah[mi], bh, acc[mi][nf]);
            }
        }
        __syncthreads();
    }

    // ---- epilogue: through-LDS transpose to swizzled 8KB tiles ----
    const int bbase = (m0 >> 11) * NH;
    const int sbase = m0 & 2047;
    short* ep = smem;   // [128][136]
    if (z < 2) {
        #pragma unroll
        for (int pass = 0; pass < 2; pass++) {
            __syncthreads();
            #pragma unroll
            for (int mi = 0; mi < 4; mi++)
                #pragma unroll
                for (int nf = 0; nf < 4; nf++)
                    #pragma unroll
                    for (int r = 0; r < 4; r++) {
                        int rl  = 64*wm + 16*mi + 4*g + r;
                        int col = 64*wn + 16*nf + c;
                        short hh, ll; splitf(acc[mi][nf][r], hh, ll);
                        ep[rl*136 + col] = pass ? ll : hh;
                    }
            __syncthreads();
            int rl2 = tid >> 1, half = tid & 1;
            int head = blockIdx.y * 2 + half;
            int s = sbase + rl2;
            int t = s >> 6, sr = s & 63, sw2 = (sr & 7) << 4;
            short* dst = pass ? (z ? ktl : qtl) : (z ? kth : qth);
            char* base = (char*)dst + ((size_t)(bbase + head) * 32 + t) * 8192 + sr * 128;
            const short* row = &ep[rl2*136 + half*64];
            #pragma unroll
            for (int ch = 0; ch < 8; ch++)
                *(bf16x8*)(base + ((ch*16) ^ sw2)) = *(const bf16x8*)(row + ch*8);
        }
    } else {
        __syncthreads();
        #pragma unroll
        for (int mi = 0; mi < 4; mi++)
            #pragma unroll
            for (int nf = 0; nf < 4; nf++)
                #pragma unroll
                for (int r = 0; r < 4; r++) {
                    int rl  = 64*wm + 16*mi + 4*g + r;
                    int col = 64*wn + 16*nf + c;
                    ep[rl*136 + col] = (short)f2bf(acc[mi][nf][r]);
                }
        __syncthreads();
        int col = tid >> 1, tt = tid & 1;
        int head = blockIdx.y * 2 + (col >> 6), dk = col & 63;
        int s0_ = sbase + tt * 64;
        int t = s0_ >> 6;
        char* base = (char*)vt + ((size_t)(bbase + head) * 32 + t) * 8192 + dk * 128;
        int sw2 = (dk & 7) << 4;
        #pragma unroll
        for (int ch = 0; ch < 8; ch++) {
            bf16x8 vv;
            #pragma unroll
            for (int i = 0; i < 8; i++) vv[i] = ep[(tt*64 + ch*8 + i)*136 + col];
            *(bf16x8*)(base + ((ch*16) ^ sw2)) = vv;
        }
    }
}

// ---------------------------------------------------------------------------
// attn_kernel: flash attention, 64 q-rows/block (4 waves x 16q). Register-
// staged K/V pipeline; raw-domain online softmax with defer-max + tile-skip;
// swizzled zero-conflict LDS; setprio(1) around MFMA clusters (T5).
// ---------------------------------------------------------------------------
__global__ __launch_bounds__(256, 4) void attn_kernel(
    const short* __restrict__ qth, const short* __restrict__ qtl,
    const short* __restrict__ kth, const short* __restrict__ ktl,
    const short* __restrict__ vtl, short* __restrict__ ao)
{
    const int orig = blockIdx.x;
    const int wg = (orig & 7) * 128 + (orig >> 3);
    const int bh = wg >> 5, qb = (wg & 31) * 64;
    const int tid = threadIdx.x;
    const int w = tid >> 6, lane = tid & 63, c = lane & 15, g = lane >> 4;

    __shared__ __align__(16) short kh_s[64*64];
    __shared__ __align__(16) short kl_s[64*64];
    __shared__ __align__(16) short v_s [64*64];
    __shared__ __align__(16) short pb  [4][16*64];
    char* khb = (char*)kh_s;
    char* klb = (char*)kl_s;
    char* vb  = (char*)v_s;
    char* pwb = (char*)pb[w];
    short* pw = pb[w];

    bf16x8 qh[2], ql[2];
    {
        const char* qtbh = (const char*)qth + ((size_t)bh*32 + (qb>>6))*8192;
        const char* qtbl = (const char*)qtl + ((size_t)bh*32 + (qb>>6))*8192;
        int s_in = 16*w + c;
        int sw = (s_in & 7) << 4;
        qh[0] = *(const bf16x8*)(qtbh + s_in*128 + ((16*g) ^ sw));
        qh[1] = *(const bf16x8*)(qtbh + s_in*128 + ((64 + 16*g) ^ sw));
        ql[0] = *(const bf16x8*)(qtbl + s_in*128 + ((16*g) ^ sw));
        ql[1] = *(const bf16x8*)(qtbl + s_in*128 + ((64 + 16*g) ^ sw));
    }

    const char* kg = (const char*)kth + (size_t)bh * 262144;
    const char* lg = (const char*)ktl + (size_t)bh * 262144;
    const char* vg = (const char*)vtl + (size_t)bh * 262144;
    const int thr = w * 2048 + lane * 16;

    const float SC = 0.18033688f;   // 0.125 * log2(e)
    float mrow[4], lrowp[4];
    f32x4 acc[4];
    #pragma unroll
    for (int r = 0; r < 4; r++) { mrow[r] = -1e30f; lrowp[r] = 0.f; }
    #pragma unroll
    for (int nf = 0; nf < 4; nf++) acc[nf] = f32x4{0.f,0.f,0.f,0.f};

    i32x4 s0, s1, s2, s3, s4, s5;
    {
        const char* p = kg + thr; s0 = *(const i32x4*)p; s1 = *(const i32x4*)(p + 1024);
        p = lg + thr;             s2 = *(const i32x4*)p; s3 = *(const i32x4*)(p + 1024);
        p = vg + thr;             s4 = *(const i32x4*)p; s5 = *(const i32x4*)(p + 1024);
    }

    for (int t = 0; t < 32; ++t) {
        {   // publish staged regs -> LDS
            char* d = khb + thr; *(i32x4*)d = s0; *(i32x4*)(d + 1024) = s1;
            d = klb + thr;       *(i32x4*)d = s2; *(i32x4*)(d + 1024) = s3;
            d = vb + thr;        *(i32x4*)d = s4; *(i32x4*)(d + 1024) = s5;
        }
        __syncthreads();
        if (t < 31) {   // prefetch next tile into regs (hides under compute)
            size_t off = (size_t)(t + 1) * 8192 + thr;
            const char* p = kg + off; s0 = *(const i32x4*)p; s1 = *(const i32x4*)(p + 1024);
            p = lg + off;             s2 = *(const i32x4*)p; s3 = *(const i32x4*)(p + 1024);
            p = vg + off;             s4 = *(const i32x4*)p; s5 = *(const i32x4*)(p + 1024);
        }

        // scores: S[16q x 64s], split 3-term MFMA over dk=64 (raw domain)
        f32x4 s4c[4];
        __builtin_amdgcn_s_setprio(1);
        #pragma unroll
        for (int sf = 0; sf < 4; sf++) {
            s4c[sf] = f32x4{0.f,0.f,0.f,0.f};
            int rowK = c + 16*sf;
            #pragma unroll
            for (int ks = 0; ks < 2; ks++) {
                int cb = (ks*64 + 16*g) ^ ((rowK & 7) << 4);
                bf16x8 kh = *(bf16x8*)(khb + rowK*128 + cb);
                bf16x8 kl = *(bf16x8*)(klb + rowK*128 + cb);
                s4c[sf] = mfma16(qh[ks], kh, s4c[sf]);
                s4c[sf] = mfma16(qh[ks], kl, s4c[sf]);
                s4c[sf] = mfma16(ql[ks], kh, s4c[sf]);
            }
        }
        __builtin_amdgcn_s_setprio(0);

        // per-row tile max (raw domain)
        float tmax[4];
        #pragma unroll
        for (int r = 0; r < 4; r++) {
            float v = fmaxf(fmaxf(s4c[0][r], s4c[1][r]), fmaxf(s4c[2][r], s4c[3][r]));
            #pragma unroll
            for (int off = 1; off < 16; off <<= 1) v = fmaxf(v, __shfl_xor(v, off));
            tmax[r] = v;
        }
        float dmax = fmaxf(fmaxf(tmax[0]-mrow[0], tmax[1]-mrow[1]),
                           fmaxf(tmax[2]-mrow[2], tmax[3]-mrow[3]));
        // skip tile if contribution < 2^-26 of running max for every row
        if (!__all(dmax < -144.0f)) {
            if (__any(dmax > 64.0f)) {   // defer-max rescale (~11.5 log2 units)
                #pragma unroll
                for (int r = 0; r < 4; r++) {
                    float mn = fmaxf(mrow[r], tmax[r]);
                    float fc = exp2_fast((mrow[r] - mn) * SC);
                    mrow[r] = mn; lrowp[r] *= fc;
                    acc[0][r] *= fc; acc[1][r] *= fc; acc[2][r] *= fc; acc[3][r] *= fc;
                }
            }
            float mS[4];
            #pragma unroll
            for (int r = 0; r < 4; r++) mS[r] = mrow[r] * SC;
            float rs[4] = {0.f, 0.f, 0.f, 0.f};
            #pragma unroll
            for (int sf = 0; sf < 4; sf++) {
                #pragma unroll
                for (int r = 0; r < 4; r++) {
                    float p = exp2_fast(fmaf(s4c[sf][r], SC, -mS[r]));
                    rs[r] += p;
                    int q = 4*g + r;
                    *(short*)(pwb + q*128 + ((2*c + 32*sf) ^ ((q & 7) << 4))) =
                        (short)(__float_as_uint(p) >> 16);
                }
            }
            #pragma unroll
            for (int r = 0; r < 4; r++) lrowp[r] += rs[r];   // per-lane partial

            // PV: out[16q x 64dk] += P[16q x 64s] @ V[64s x 64dk]
            __builtin_amdgcn_s_setprio(1);
            #pragma unroll
            for (int ks = 0; ks < 2; ks++) {
                int cbp = (ks*64 + 16*g) ^ ((c & 7) << 4);
                bf16x8 pa = *(bf16x8*)(pwb + c*128 + cbp);
                #pragma unroll
                for (int nf = 0; nf < 4; nf++) {
                    int rowV = c + 16*nf;
                    int cbv = (ks*64 + 16*g) ^ ((rowV & 7) << 4);
                    bf16x8 vv = *(bf16x8*)(vb + rowV*128 + cbv);
                    acc[nf] = mfma16(pa, vv, acc[nf]);
                }
            }
            __builtin_amdgcn_s_setprio(0);
        }
        __syncthreads();
    }

    // epilogue: cross-lane lrow reduction, normalize, LDS-transpose, 16B stores
    float inv[4];
    #pragma unroll
    for (int r = 0; r < 4; r++) {
        float t2 = lrowp[r];
        #pragma unroll
        for (int off = 1; off < 16; off <<= 1) t2 += __shfl_xor(t2, off);
        inv[r] = 1.f / t2;
    }
    #pragma unroll
    for (int nf = 0; nf < 4; nf++)
        #pragma unroll
        for (int r = 0; r < 4; r++)
            pw[(4*g + r)*64 + c + 16*nf] = (short)f2bf(acc[nf][r] * inv[r]);

    const int b = bh >> 3, hh = bh & 7;
    {
        int q = qb + 16*w + c;
        size_t o = ((size_t)b * NS + q) * ND + hh * NDK + g * 16;
        const short* src = pw + c*64 + g*16;
        *(bf16x8*)&ao[o]     = *(const bf16x8*)src;
        *(bf16x8*)&ao[o + 8] = *(const bf16x8*)(src + 8);
    }
}

// ---------------------------------------------------------------------------
// oproj_kernel: out[8192x512] = ao(bf16) @ WO(f32->bf16). Tile 128x64.
// ---------------------------------------------------------------------------
__global__ __launch_bounds__(256) void oproj_kernel(
    const short* __restrict__ ao, const float* __restrict__ WO, float* __restrict__ out)
{
    const int orig = blockIdx.x;
    const int wg = (orig & 7) * 64 + (orig >> 3);
    const int mb = (wg >> 3) * 128, nb = (wg & 7) * 64;
    const int tid = threadIdx.x;
    const int w = tid >> 6, lane = tid & 63, c = lane & 15, g = lane >> 4;

    __shared__ __align__(16) short xlds[128*40];
    __shared__ __align__(16) short wt[64*40];

    f32x4 acc[2][4];
    #pragma unroll
    for (int i = 0; i < 2; i++)
        #pragma unroll
        for (int j = 0; j < 4; j++) acc[i][j] = f32x4{0.f,0.f,0.f,0.f};

    for (int k0 = 0; k0 < ND; k0 += 32) {
        {
            int r = tid >> 1, kq = (tid & 1) * 16;
            const short* src = ao + (size_t)(mb + r) * ND + k0 + kq;
            *(bf16x8*)&xlds[r*40 + kq]     = *(const bf16x8*)src;
            *(bf16x8*)&xlds[r*40 + kq + 8] = *(const bf16x8*)(src + 8);
        }
        #pragma unroll
        for (int i = 0; i < 2; i++) {
            int idx = tid * 2 + i;
            int kr = idx >> 4, c4 = (idx & 15) * 4;
            float4 f = *(const float4*)&WO[(size_t)(k0 + kr) * ND + nb + c4];
            wt[(c4+0)*40 + kr] = (short)f2bf(f.x);
            wt[(c4+1)*40 + kr] = (short)f2bf(f.y);
            wt[(c4+2)*40 + kr] = (short)f2bf(f.z);
            wt[(c4+3)*40 + kr] = (short)f2bf(f.w);
        }
        __syncthreads();
        bf16x8 a0 = *(bf16x8*)&xlds[(32*w +      c)*40 + 8*g];
        bf16x8 a1 = *(bf16x8*)&xlds[(32*w + 16 + c)*40 + 8*g];
        #pragma unroll
        for (int nf = 0; nf < 4; nf++) {
            bf16x8 bv = *(bf16x8*)&wt[(c + 16*nf)*40 + 8*g];
            acc[0][nf] = mfma16(a0, bv, acc[0][nf]);
            acc[1][nf] = mfma16(a1, bv, acc[1][nf]);
        }
        __syncthreads();
    }
    #pragma unroll
    for (int mi = 0; mi < 2; mi++)
        #pragma unroll
        for (int nf = 0; nf < 4; nf++)
            #pragma unroll
            for (int r = 0; r < 4; r++) {
                int row = mb + 32*w + 16*mi + 4*g + r;
                out[(size_t)row * ND + nb + c + 16*nf] = acc[mi][nf][r];
            }
}

extern "C" void kernel_launch(void* const* d_in, const int* in_sizes, int n_in,
                              void* d_out, int out_size, void* d_ws, size_t ws_size,
                              hipStream_t stream) {
    (void)in_sizes; (void)n_in; (void)out_size; (void)ws_size;
    const float* Q  = (const float*)d_in[0];
    const float* K  = (const float*)d_in[1];
    const float* V  = (const float*)d_in[2];
    const float* WQ = (const float*)d_in[3];
    const float* WK = (const float*)d_in[4];
    const float* WV = (const float*)d_in[5];
    const float* WO = (const float*)d_in[6];

    char* ws = (char*)d_ws;
    const size_t PLANE = (size_t)NB * NH * NS * NDK * 2;   // 8,388,608 B (x6 = proven 50.3 MB)
    short* qth = (short*)(ws);
    short* qtl = (short*)(ws +     PLANE);
    short* kth = (short*)(ws + 2 * PLANE);
    short* ktl = (short*)(ws + 3 * PLANE);
    short* vt  = (short*)(ws + 4 * PLANE);
    short* ao  = (short*)(ws + 5 * PLANE);

    // weight planes live in d_out (16.8 MB scratch, dead until oproj which
    // reads none of them and fully overwrites d_out)
    short* wqh = (short*)d_out;            // 5 x 512 KB = 2.62 MB
    short* wql = wqh + 262144;
    short* wkh = wqh + 2 * 262144;
    short* wkl = wqh + 3 * 262144;
    short* wv  = wqh + 4 * 262144;

    prep_w<<<dim3(256, 3), 256, 0, stream>>>(WQ, WK, WV, wqh, wql, wkh, wkl, wv);
    proj<<<dim3(64, 4, 3), 256, 0, stream>>>(Q, K, V, wqh, wql, wkh, wkl, wv,
                                             qth, qtl, kth, ktl, vt);
    attn_kernel<<<1024, 256, 0, stream>>>(qth, qtl, kth, ktl, vt, ao);
    oproj_kernel<<<512, 256, 0, stream>>>(ao, WO, (float*)d_out);
}